// Round 14
// baseline (104.628 us; speedup 1.0000x reference)
//
#include <hip/hip_runtime.h>

#define N_NODES 50000
#define N_EDGES 800000
#define NF 128
#define N_GRAPHS 512
#define STRIDE 64        // fixed CSR slots/node; P(deg>64) ~ 1e-13 for Poisson(16)

#define NBINS 391        // ceil(50000/128) bins of 128 nodes (dst>>7)
#define NBLK 196         // edge blocks: ceil(800000/4096)
#define EPB 4096         // edges per block in binning pass
#define BINCAP 2560      // slots per bin; mean 2048, sigma 45 -> 11 sigma pad

typedef _Float16 f16;
typedef f16 h2    __attribute__((ext_vector_type(2)));
typedef f16 f16x8 __attribute__((ext_vector_type(8)));
typedef float f32x4 __attribute__((ext_vector_type(4)));

union HU { ushort u; _Float16 h; };
__device__ __forceinline__ float h2f(ushort u) { HU x; x.u = u; return (float)x.h; }
__device__ __forceinline__ ushort f2h(float f) { HU x; x.h = (_Float16)f; return x.u; }

// packed fp16 accumulate: 4 v_pk_add_f16 per 16B
union UH2 { uint u; h2 h; };
__device__ __forceinline__ void acc4h(h2* ah, uint4 u) {
  UH2 c;
  c.u = u.x; ah[0] += c.h;
  c.u = u.y; ah[1] += c.h;
  c.u = u.z; ah[2] += c.h;
  c.u = u.w; ah[3] += c.h;
}

// ---------------- v[f] = sum_j W2[f][j] * Wfc[j] ------------------------------
__global__ __launch_bounds__(128) void w2wfc(const float* __restrict__ W2,
                                             const float* __restrict__ Wfc,
                                             float* __restrict__ v) {
  int f = threadIdx.x;
  float s = 0.f;
  for (int j = 0; j < 128; j += 4) {
    float4 w = ((const float4*)(W2 + f * 128))[j >> 2];
    float4 c = ((const float4*)Wfc)[j >> 2];
    s += w.x * c.x + w.y * c.y + w.z * c.z + w.w * c.w;
  }
  v[f] = s;
}

// ---------------- W1 (f32 [k][n]) -> W1T (fp16 [n][k]) ------------------------
__global__ __launch_bounds__(256) void w1cvt(const float* __restrict__ W1,
                                             ushort* __restrict__ W1T) {
  int i = blockIdx.x * 256 + threadIdx.x;   // 64 blocks x 256 = 16384
  int n = i >> 7, k = i & 127;
  W1T[i] = f2h(W1[k * 128 + n]);
}

// ======== CSR build A: single-pass binning with chunk reservation ============
__global__ __launch_bounds__(256) void bin_scatter2(const int* __restrict__ src,
                                                    const int* __restrict__ dst,
                                                    int* __restrict__ gcur,
                                                    uint* __restrict__ ebuf) {
  __shared__ int hist[NBINS];
  __shared__ int base[NBINS];
  for (int i = threadIdx.x; i < NBINS; i += 256) hist[i] = 0;
  __syncthreads();
  int e0 = blockIdx.x * EPB;
  int e1 = e0 + EPB; if (e1 > N_EDGES) e1 = N_EDGES;
  for (int e = e0 + threadIdx.x; e < e1; e += 256)
    atomicAdd(&hist[dst[e] >> 7], 1);
  __syncthreads();
  for (int i = threadIdx.x; i < NBINS; i += 256) {
    int c = hist[i];
    base[i] = (c > 0) ? atomicAdd(&gcur[i], c) : 0;
    hist[i] = 0;
  }
  __syncthreads();
  for (int e = e0 + threadIdx.x; e < e1; e += 256) {
    int d = dst[e];
    int b = d >> 7;
    int loc = atomicAdd(&hist[b], 1);
    ebuf[(size_t)b * BINCAP + base[b] + loc] = ((uint)d << 16) | (uint)src[e];
  }
}

// ======== CSR build B: one block per bin -> col16 window + deg ===============
__global__ __launch_bounds__(256) void csr_from_bins(const uint* __restrict__ ebuf,
                                                     const int* __restrict__ gcur,
                                                     int* __restrict__ deg,
                                                     ushort* __restrict__ col16) {
  __shared__ int dl[128];
  const int bin = blockIdx.x;
  const int n0 = bin << 7;
  if (threadIdx.x < 128) dl[threadIdx.x] = 0;
  __syncthreads();
  int cnt_e = gcur[bin];
  int j0 = bin * BINCAP;
  for (int j = j0 + threadIdx.x; j < j0 + cnt_e; j += 256) {
    uint e = ebuf[j];
    int d = (int)(e >> 16);
    int slot = atomicAdd(&dl[d - n0], 1);
    col16[(size_t)d * STRIDE + slot] = (ushort)(e & 0xFFFFu);
  }
  __syncthreads();
  int cnt = N_NODES - n0; if (cnt > 128) cnt = 128;
  if (threadIdx.x < cnt) deg[n0 + threadIdx.x] = dl[threadIdx.x];
}

// -------- MFMA GEMM: y16 = x @ W1 (fp16 in, f32 acc, fp16 out) ---------------
// Epilogue repacks through LDS so global stores are coalesced uint2.
__global__ __launch_bounds__(256) void gemm_mfma(const float* __restrict__ x,
                                                 const ushort* __restrict__ W1T,
                                                 ushort* __restrict__ y16, int M) {
  __shared__ ushort ly[4][16][136];
  const int tid = threadIdx.x;
  const int w = tid >> 6, l = tid & 63;
  const int row0 = blockIdx.x * 64 + w * 16;
  const int mrow = l & 15, kg = l >> 4;
  const int row = row0 + mrow;

  f32x4 acc[8] = {};
  for (int kc = 0; kc < 4; ++kc) {
    const int cb = kc * 32 + kg * 8;
    f16x8 af = {};
    if (row < M) {
      float4 xlo = *(const float4*)(x + (size_t)row * 128 + cb);
      float4 xhi = *(const float4*)(x + (size_t)row * 128 + cb + 4);
      af[0] = (f16)xlo.x; af[1] = (f16)xlo.y; af[2] = (f16)xlo.z; af[3] = (f16)xlo.w;
      af[4] = (f16)xhi.x; af[5] = (f16)xhi.y; af[6] = (f16)xhi.z; af[7] = (f16)xhi.w;
    }
#pragma unroll
    for (int nt = 0; nt < 8; ++nt) {
      uint4 wb = *(const uint4*)(W1T + ((nt * 16 + mrow) << 7) + cb);
      f16x8 bf = *(const f16x8*)&wb;
      acc[nt] = __builtin_amdgcn_mfma_f32_16x16x32_f16(af, bf, acc[nt], 0, 0, 0);
    }
  }
  // D layout: col = lane&15 (mrow), row = (lane>>4)*4 + r (kg)
#pragma unroll
  for (int nt = 0; nt < 8; ++nt)
#pragma unroll
    for (int r = 0; r < 4; ++r)
      ly[w][kg * 4 + r][nt * 16 + mrow] = f2h(acc[nt][r]);
  __syncthreads();
  // coalesced store: 16 rows x 32 uint2 per wave, 8 per lane
  // uint2 = 4 ushorts -> source ushort index is c2*4 (R13 bug was c2*2)
#pragma unroll
  for (int t = 0; t < 8; ++t) {
    int idx = t * 64 + l;
    int r2 = idx >> 5, c2 = idx & 31;
    int gr = row0 + r2;
    if (gr < M)
      ((uint2*)y16)[(size_t)gr * 32 + c2] = *(const uint2*)&ly[w][r2][c2 * 4];
  }
}

// ------- gather + relu + dot: q[n] = relu( sum_slots y16[col16[n][j]] ) . v --
__global__ __launch_bounds__(256) void gather_qdot(const ushort* __restrict__ y16,
                                                   const int* __restrict__ deg,
                                                   const ushort* __restrict__ col16,
                                                   const float* __restrict__ vq,
                                                   float* __restrict__ q) {
  int n = (blockIdx.x * 256 + threadIdx.x) >> 6;
  if (n >= N_NODES) return;
  const int lane = threadIdx.x & 63;
  const int eg = lane >> 4;    // 0..3 edge group
  const int fl = lane & 15;    // feat lane: 8 fp16 = 16B

  int dg = deg[n];
  const ushort* cp = col16 + (size_t)n * STRIDE;
  h2 ah[4] = {};

  int j = eg;
  for (; j + 4 < dg; j += 8) {
    int s0 = cp[j], s1 = cp[j + 4];
    uint4 a = ((const uint4*)y16)[(size_t)s0 * 16 + fl];
    uint4 b = ((const uint4*)y16)[(size_t)s1 * 16 + fl];
    acc4h(ah, a);
    acc4h(ah, b);
  }
  if (j < dg) {
    uint4 a = ((const uint4*)y16)[(size_t)cp[j] * 16 + fl];
    acc4h(ah, a);
  }

#pragma unroll
  for (int k = 0; k < 4; ++k) {
    UH2 c, t;
    c.h = ah[k];
    t.u = (uint)__shfl_xor((int)c.u, 16, 64); ah[k] += t.h;
    c.h = ah[k];
    t.u = (uint)__shfl_xor((int)c.u, 32, 64); ah[k] += t.h;
  }
  float4 v0 = ((const float4*)vq)[fl * 2];
  float4 v1 = ((const float4*)vq)[fl * 2 + 1];
  float p = fmaxf((float)ah[0].x, 0.f) * v0.x + fmaxf((float)ah[0].y, 0.f) * v0.y +
            fmaxf((float)ah[1].x, 0.f) * v0.z + fmaxf((float)ah[1].y, 0.f) * v0.w +
            fmaxf((float)ah[2].x, 0.f) * v1.x + fmaxf((float)ah[2].y, 0.f) * v1.y +
            fmaxf((float)ah[3].x, 0.f) * v1.z + fmaxf((float)ah[3].y, 0.f) * v1.w;
  p += __shfl_xor(p, 1, 64);
  p += __shfl_xor(p, 2, 64);
  p += __shfl_xor(p, 4, 64);
  p += __shfl_xor(p, 8, 64);
  if (lane == 0) q[n] = p;
}

// ------- pool: out[g] = sigmoid( (sum over graph-g edges of q[src]) / cnt ) --
__global__ __launch_bounds__(256) void pool_q(const float* __restrict__ q,
                                              const int* __restrict__ deg,
                                              const ushort* __restrict__ col16,
                                              const int* __restrict__ batch,
                                              float* __restrict__ out) {
  __shared__ float red[4];
  int g = blockIdx.x, tid = threadIdx.x;

  int lo = 0, hi = N_NODES;
  while (lo < hi) { int m = (lo + hi) >> 1; if (batch[m] < g) lo = m + 1; else hi = m; }
  int s0 = lo;
  lo = 0; hi = N_NODES;
  while (lo < hi) { int m = (lo + hi) >> 1; if (batch[m] <= g) lo = m + 1; else hi = m; }
  int s1 = lo;

  float sum = 0.f;
  for (int n = s0 + (tid >> 3); n < s1; n += 32) {
    int dg = deg[n];
    const ushort* cp = col16 + (size_t)n * STRIDE;
    for (int j = tid & 7; j < dg; j += 8) sum += q[cp[j]];
  }
#pragma unroll
  for (int off = 32; off > 0; off >>= 1) sum += __shfl_down(sum, off, 64);
  if ((tid & 63) == 0) red[tid >> 6] = sum;
  __syncthreads();
  if (tid == 0) {
    float z = red[0] + red[1] + red[2] + red[3];
    float cnt = fmaxf((float)(s1 - s0), 1.0f);
    z /= cnt;
    out[g] = 1.0f / (1.0f + expf(-z));
  }
}

extern "C" void kernel_launch(void* const* d_in, const int* in_sizes, int n_in,
                              void* d_out, int out_size, void* d_ws, size_t ws_size,
                              hipStream_t stream) {
  const float* x   = (const float*)d_in[0];
  const int*   ei  = (const int*)d_in[1];
  const int*   src = ei;               // edge_index[0]
  const int*   dst = ei + N_EDGES;     // edge_index[1]
  const int* batch = (const int*)d_in[2];
  const float* W1  = (const float*)d_in[3];
  const float* W2  = (const float*)d_in[4];
  const float* Wfc = (const float*)d_in[5];
  float* out = (float*)d_out;

  ushort* y16  = (ushort*)d_ws;                          // 6.4M fp16
  ushort* col16 = y16 + (size_t)N_NODES * NF;            // 50000*64 ushort
  int* deg     = (int*)(col16 + (size_t)N_NODES * STRIDE); // 50000
  float* q     = (float*)(deg + N_NODES);                // 50000
  float* v     = q + N_NODES;                            // 128
  ushort* W1T  = (ushort*)(v + NF + 32);                 // 16384 fp16
  int* gcur    = (int*)(W1T + 16384 + 64);               // NBINS
  uint* ebuf   = (uint*)(gcur + NBINS + 32);             // NBINS*BINCAP u32

  const int gemm_grid = (N_NODES + 63) / 64;            // 782
  const int gath_grid = (N_NODES * 64 + 255) / 256;     // 12500

  // --- build CSR: chunk-reserved binning, then per-bin single-block fill ---
  hipMemsetAsync(gcur, 0, NBINS * sizeof(int), stream);
  bin_scatter2<<<NBLK, 256, 0, stream>>>(src, dst, gcur, ebuf);
  csr_from_bins<<<NBINS, 256, 0, stream>>>(ebuf, gcur, deg, col16);

  // --- weights prep + dense MFMA GEMM: y16 = x@W1 ---
  w2wfc<<<1, 128, 0, stream>>>(W2, Wfc, v);
  w1cvt<<<64, 256, 0, stream>>>(W1, W1T);
  gemm_mfma<<<gemm_grid, 256, 0, stream>>>(x, W1T, y16, N_NODES);

  // --- conv1 aggregate + relu + (W2@Wfc) dot, fused per node ---
  gather_qdot<<<gath_grid, 256, 0, stream>>>(y16, deg, col16, v, q);

  // --- conv2 + pool + fc + sigmoid: scalar gather over L2-resident q ---
  pool_q<<<N_GRAPHS, 256, 0, stream>>>(q, deg, col16, batch, out);
}

// Round 15
// 96.162 us; speedup vs baseline: 1.0880x; 1.0880x over previous
//
#include <hip/hip_runtime.h>

#define N_NODES 50000
#define N_EDGES 800000
#define NF 128
#define N_GRAPHS 512
#define STRIDE 64        // fixed CSR slots/node; P(deg>64) ~ 1e-13 for Poisson(16)

#define NBINS 391        // ceil(50000/128) bins of 128 nodes (dst>>7)
#define NBLK 196         // edge blocks: ceil(800000/4096)
#define EPB 4096         // edges per block in binning pass
#define BINCAP 2560      // slots per bin; mean 2048, sigma 45 -> 11 sigma pad

typedef _Float16 f16;
typedef f16 h2    __attribute__((ext_vector_type(2)));
typedef f16 f16x8 __attribute__((ext_vector_type(8)));
typedef float f32x4 __attribute__((ext_vector_type(4)));

union HU { ushort u; _Float16 h; };
__device__ __forceinline__ float h2f(ushort u) { HU x; x.u = u; return (float)x.h; }
__device__ __forceinline__ ushort f2h(float f) { HU x; x.h = (_Float16)f; return x.u; }

// packed fp16 accumulate: 4 v_pk_add_f16 per 16B
union UH2 { uint u; h2 h; };
__device__ __forceinline__ void acc4h(h2* ah, uint4 u) {
  UH2 c;
  c.u = u.x; ah[0] += c.h;
  c.u = u.y; ah[1] += c.h;
  c.u = u.z; ah[2] += c.h;
  c.u = u.w; ah[3] += c.h;
}

// ---- prep: blocks 0-63 W1->W1T(fp16,[n][k]); block 64 v=W2@Wfc; 65 zero gcur
__global__ __launch_bounds__(256) void prep(const float* __restrict__ W1,
                                            const float* __restrict__ W2,
                                            const float* __restrict__ Wfc,
                                            ushort* __restrict__ W1T,
                                            float* __restrict__ v,
                                            int* __restrict__ gcur) {
  int b = blockIdx.x;
  if (b < 64) {
    int i = b * 256 + threadIdx.x;      // 16384 total
    int n = i >> 7, k = i & 127;
    W1T[i] = f2h(W1[k * 128 + n]);
  } else if (b == 64) {
    if (threadIdx.x < 128) {
      int f = threadIdx.x;
      float s = 0.f;
      for (int j = 0; j < 128; j += 4) {
        float4 w = ((const float4*)(W2 + f * 128))[j >> 2];
        float4 c = ((const float4*)Wfc)[j >> 2];
        s += w.x * c.x + w.y * c.y + w.z * c.z + w.w * c.w;
      }
      v[f] = s;
    }
  } else {
    for (int i = threadIdx.x; i < NBINS; i += 256) gcur[i] = 0;
  }
}

// ======== CSR build A: single-pass binning with chunk reservation ============
__global__ __launch_bounds__(256) void bin_scatter2(const int* __restrict__ src,
                                                    const int* __restrict__ dst,
                                                    int* __restrict__ gcur,
                                                    uint* __restrict__ ebuf) {
  __shared__ int hist[NBINS];
  __shared__ int base[NBINS];
  for (int i = threadIdx.x; i < NBINS; i += 256) hist[i] = 0;
  __syncthreads();
  int e0 = blockIdx.x * EPB;
  int e1 = e0 + EPB; if (e1 > N_EDGES) e1 = N_EDGES;
  for (int e = e0 + threadIdx.x; e < e1; e += 256)
    atomicAdd(&hist[dst[e] >> 7], 1);
  __syncthreads();
  for (int i = threadIdx.x; i < NBINS; i += 256) {
    int c = hist[i];
    base[i] = (c > 0) ? atomicAdd(&gcur[i], c) : 0;
    hist[i] = 0;
  }
  __syncthreads();
  for (int e = e0 + threadIdx.x; e < e1; e += 256) {
    int d = dst[e];
    int b = d >> 7;
    int loc = atomicAdd(&hist[b], 1);
    ebuf[(size_t)b * BINCAP + base[b] + loc] = ((uint)d << 16) | (uint)src[e];
  }
}

// ======== CSR build B: one block per bin -> col16 window + deg ===============
__global__ __launch_bounds__(256) void csr_from_bins(const uint* __restrict__ ebuf,
                                                     const int* __restrict__ gcur,
                                                     int* __restrict__ deg,
                                                     ushort* __restrict__ col16) {
  __shared__ int dl[128];
  const int bin = blockIdx.x;
  const int n0 = bin << 7;
  if (threadIdx.x < 128) dl[threadIdx.x] = 0;
  __syncthreads();
  int cnt_e = gcur[bin];
  int j0 = bin * BINCAP;
  for (int j = j0 + threadIdx.x; j < j0 + cnt_e; j += 256) {
    uint e = ebuf[j];
    int d = (int)(e >> 16);
    int slot = atomicAdd(&dl[d - n0], 1);
    col16[(size_t)d * STRIDE + slot] = (ushort)(e & 0xFFFFu);
  }
  __syncthreads();
  int cnt = N_NODES - n0; if (cnt > 128) cnt = 128;
  if (threadIdx.x < cnt) deg[n0 + threadIdx.x] = dl[threadIdx.x];
}

// -------- MFMA GEMM: y16 = x @ W1 (fp16 in, f32 acc, fp16 out) ---------------
__global__ __launch_bounds__(256) void gemm_mfma(const float* __restrict__ x,
                                                 const ushort* __restrict__ W1T,
                                                 ushort* __restrict__ y16, int M) {
  __shared__ ushort ly[4][16][136];
  const int tid = threadIdx.x;
  const int w = tid >> 6, l = tid & 63;
  const int row0 = blockIdx.x * 64 + w * 16;
  const int mrow = l & 15, kg = l >> 4;
  const int row = row0 + mrow;

  f32x4 acc[8] = {};
  for (int kc = 0; kc < 4; ++kc) {
    const int cb = kc * 32 + kg * 8;
    f16x8 af = {};
    if (row < M) {
      float4 xlo = *(const float4*)(x + (size_t)row * 128 + cb);
      float4 xhi = *(const float4*)(x + (size_t)row * 128 + cb + 4);
      af[0] = (f16)xlo.x; af[1] = (f16)xlo.y; af[2] = (f16)xlo.z; af[3] = (f16)xlo.w;
      af[4] = (f16)xhi.x; af[5] = (f16)xhi.y; af[6] = (f16)xhi.z; af[7] = (f16)xhi.w;
    }
#pragma unroll
    for (int nt = 0; nt < 8; ++nt) {
      uint4 wb = *(const uint4*)(W1T + ((nt * 16 + mrow) << 7) + cb);
      f16x8 bf = *(const f16x8*)&wb;
      acc[nt] = __builtin_amdgcn_mfma_f32_16x16x32_f16(af, bf, acc[nt], 0, 0, 0);
    }
  }
  // D layout: col = lane&15 (mrow), row = (lane>>4)*4 + r (kg)
#pragma unroll
  for (int nt = 0; nt < 8; ++nt)
#pragma unroll
    for (int r = 0; r < 4; ++r)
      ly[w][kg * 4 + r][nt * 16 + mrow] = f2h(acc[nt][r]);
  __syncthreads();
  // coalesced store: 16 rows x 32 uint2 per wave, 8 per lane (uint2 = 4 ushort)
#pragma unroll
  for (int t = 0; t < 8; ++t) {
    int idx = t * 64 + l;
    int r2 = idx >> 5, c2 = idx & 31;
    int gr = row0 + r2;
    if (gr < M)
      ((uint2*)y16)[(size_t)gr * 32 + c2] = *(const uint2*)&ly[w][r2][c2 * 4];
  }
}

// ------- gather + relu + dot: q[n] = relu( sum_slots y16[col16[n][j]] ) . v --
// 4-deep unrolled first loop: a deg~16 node's eg-lane has <=4 slots, so all 4
// row loads issue back-to-back (16 in flight per wave).
__global__ __launch_bounds__(256) void gather_qdot(const ushort* __restrict__ y16,
                                                   const int* __restrict__ deg,
                                                   const ushort* __restrict__ col16,
                                                   const float* __restrict__ vq,
                                                   float* __restrict__ q) {
  int n = (blockIdx.x * 256 + threadIdx.x) >> 6;
  if (n >= N_NODES) return;
  const int lane = threadIdx.x & 63;
  const int eg = lane >> 4;    // 0..3 edge group
  const int fl = lane & 15;    // feat lane: 8 fp16 = 16B

  int dg = deg[n];
  const ushort* cp = col16 + (size_t)n * STRIDE;
  h2 ah[4] = {};

  int j = eg;
  for (; j + 12 < dg; j += 16) {
    int s0 = cp[j], s1 = cp[j + 4], s2 = cp[j + 8], s3 = cp[j + 12];
    uint4 a = ((const uint4*)y16)[(size_t)s0 * 16 + fl];
    uint4 b = ((const uint4*)y16)[(size_t)s1 * 16 + fl];
    uint4 c = ((const uint4*)y16)[(size_t)s2 * 16 + fl];
    uint4 d = ((const uint4*)y16)[(size_t)s3 * 16 + fl];
    acc4h(ah, a);
    acc4h(ah, b);
    acc4h(ah, c);
    acc4h(ah, d);
  }
  for (; j + 4 < dg; j += 8) {
    int s0 = cp[j], s1 = cp[j + 4];
    uint4 a = ((const uint4*)y16)[(size_t)s0 * 16 + fl];
    uint4 b = ((const uint4*)y16)[(size_t)s1 * 16 + fl];
    acc4h(ah, a);
    acc4h(ah, b);
  }
  if (j < dg) {
    uint4 a = ((const uint4*)y16)[(size_t)cp[j] * 16 + fl];
    acc4h(ah, a);
  }

#pragma unroll
  for (int k = 0; k < 4; ++k) {
    UH2 c, t;
    c.h = ah[k];
    t.u = (uint)__shfl_xor((int)c.u, 16, 64); ah[k] += t.h;
    c.h = ah[k];
    t.u = (uint)__shfl_xor((int)c.u, 32, 64); ah[k] += t.h;
  }
  float4 v0 = ((const float4*)vq)[fl * 2];
  float4 v1 = ((const float4*)vq)[fl * 2 + 1];
  float p = fmaxf((float)ah[0].x, 0.f) * v0.x + fmaxf((float)ah[0].y, 0.f) * v0.y +
            fmaxf((float)ah[1].x, 0.f) * v0.z + fmaxf((float)ah[1].y, 0.f) * v0.w +
            fmaxf((float)ah[2].x, 0.f) * v1.x + fmaxf((float)ah[2].y, 0.f) * v1.y +
            fmaxf((float)ah[3].x, 0.f) * v1.z + fmaxf((float)ah[3].y, 0.f) * v1.w;
  p += __shfl_xor(p, 1, 64);
  p += __shfl_xor(p, 2, 64);
  p += __shfl_xor(p, 4, 64);
  p += __shfl_xor(p, 8, 64);
  if (lane == 0) q[n] = p;
}

// ------- pool: out[g] = sigmoid( (sum over graph-g edges of q[src]) / cnt ) --
__global__ __launch_bounds__(256) void pool_q(const float* __restrict__ q,
                                              const int* __restrict__ deg,
                                              const ushort* __restrict__ col16,
                                              const int* __restrict__ batch,
                                              float* __restrict__ out) {
  __shared__ float red[4];
  int g = blockIdx.x, tid = threadIdx.x;

  int lo = 0, hi = N_NODES;
  while (lo < hi) { int m = (lo + hi) >> 1; if (batch[m] < g) lo = m + 1; else hi = m; }
  int s0 = lo;
  lo = 0; hi = N_NODES;
  while (lo < hi) { int m = (lo + hi) >> 1; if (batch[m] <= g) lo = m + 1; else hi = m; }
  int s1 = lo;

  float sum = 0.f;
  for (int n = s0 + (tid >> 3); n < s1; n += 32) {
    int dg = deg[n];
    const ushort* cp = col16 + (size_t)n * STRIDE;
    for (int j = tid & 7; j < dg; j += 8) sum += q[cp[j]];
  }
#pragma unroll
  for (int off = 32; off > 0; off >>= 1) sum += __shfl_down(sum, off, 64);
  if ((tid & 63) == 0) red[tid >> 6] = sum;
  __syncthreads();
  if (tid == 0) {
    float z = red[0] + red[1] + red[2] + red[3];
    float cnt = fmaxf((float)(s1 - s0), 1.0f);
    z /= cnt;
    out[g] = 1.0f / (1.0f + expf(-z));
  }
}

extern "C" void kernel_launch(void* const* d_in, const int* in_sizes, int n_in,
                              void* d_out, int out_size, void* d_ws, size_t ws_size,
                              hipStream_t stream) {
  const float* x   = (const float*)d_in[0];
  const int*   ei  = (const int*)d_in[1];
  const int*   src = ei;               // edge_index[0]
  const int*   dst = ei + N_EDGES;     // edge_index[1]
  const int* batch = (const int*)d_in[2];
  const float* W1  = (const float*)d_in[3];
  const float* W2  = (const float*)d_in[4];
  const float* Wfc = (const float*)d_in[5];
  float* out = (float*)d_out;

  ushort* y16  = (ushort*)d_ws;                          // 6.4M fp16
  ushort* col16 = y16 + (size_t)N_NODES * NF;            // 50000*64 ushort
  int* deg     = (int*)(col16 + (size_t)N_NODES * STRIDE); // 50000
  float* q     = (float*)(deg + N_NODES);                // 50000
  float* v     = q + N_NODES;                            // 128
  ushort* W1T  = (ushort*)(v + NF + 32);                 // 16384 fp16
  int* gcur    = (int*)(W1T + 16384 + 64);               // NBINS
  uint* ebuf   = (uint*)(gcur + NBINS + 32);             // NBINS*BINCAP u32

  const int gemm_grid = (N_NODES + 63) / 64;            // 782
  const int gath_grid = (N_NODES * 64 + 255) / 256;     // 12500

  // --- prep: W1T, v, gcur=0 in one kernel ---
  prep<<<66, 256, 0, stream>>>(W1, W2, Wfc, W1T, v, gcur);

  // --- build CSR: chunk-reserved binning, then per-bin single-block fill ---
  bin_scatter2<<<NBLK, 256, 0, stream>>>(src, dst, gcur, ebuf);
  csr_from_bins<<<NBINS, 256, 0, stream>>>(ebuf, gcur, deg, col16);

  // --- dense MFMA GEMM: y16 = x@W1 ---
  gemm_mfma<<<gemm_grid, 256, 0, stream>>>(x, W1T, y16, N_NODES);

  // --- conv1 aggregate + relu + (W2@Wfc) dot, fused per node ---
  gather_qdot<<<gath_grid, 256, 0, stream>>>(y16, deg, col16, v, q);

  // --- conv2 + pool + fc + sigmoid: scalar gather over L2-resident q ---
  pool_q<<<N_GRAPHS, 256, 0, stream>>>(q, deg, col16, batch, out);
}

// Round 16
// 86.880 us; speedup vs baseline: 1.2043x; 1.1068x over previous
//
#include <hip/hip_runtime.h>

#define N_NODES 50000
#define N_EDGES 800000
#define NF 128
#define N_GRAPHS 512
#define STRIDE 64        // fixed CSR slots/node; P(deg>64) ~ 1e-13 for Poisson(16)

#define NBINS 391        // ceil(50000/128) bins of 128 nodes (dst>>7)
#define NBLK 196         // edge blocks: ceil(800000/4096)
#define EPB 4096         // edges per block in binning pass
#define BINCAP 2560      // slots per bin; mean 2048, sigma 45 -> 11 sigma pad

typedef _Float16 f16;
typedef f16 h2    __attribute__((ext_vector_type(2)));
typedef f16 f16x8 __attribute__((ext_vector_type(8)));
typedef float f32x4 __attribute__((ext_vector_type(4)));

union HU { ushort u; _Float16 h; };
__device__ __forceinline__ float h2f(ushort u) { HU x; x.u = u; return (float)x.h; }
__device__ __forceinline__ ushort f2h(float f) { HU x; x.h = (_Float16)f; return x.u; }

// packed fp16 accumulate: 4 v_pk_add_f16 per 16B
union UH2 { uint u; h2 h; };
__device__ __forceinline__ void acc4h(h2* ah, uint4 u) {
  UH2 c;
  c.u = u.x; ah[0] += c.h;
  c.u = u.y; ah[1] += c.h;
  c.u = u.z; ah[2] += c.h;
  c.u = u.w; ah[3] += c.h;
}

// ---- prep: blocks 0-63 W1->W1T(fp16,[n][k]); block 64 v=W2@Wfc; 65 zero gcur
__global__ __launch_bounds__(256) void prep(const float* __restrict__ W1,
                                            const float* __restrict__ W2,
                                            const float* __restrict__ Wfc,
                                            ushort* __restrict__ W1T,
                                            float* __restrict__ v,
                                            int* __restrict__ gcur) {
  int b = blockIdx.x;
  if (b < 64) {
    int i = b * 256 + threadIdx.x;      // 16384 total
    int n = i >> 7, k = i & 127;
    W1T[i] = f2h(W1[k * 128 + n]);
  } else if (b == 64) {
    if (threadIdx.x < 128) {
      int f = threadIdx.x;
      float s = 0.f;
      for (int j = 0; j < 128; j += 4) {
        float4 w = ((const float4*)(W2 + f * 128))[j >> 2];
        float4 c = ((const float4*)Wfc)[j >> 2];
        s += w.x * c.x + w.y * c.y + w.z * c.z + w.w * c.w;
      }
      v[f] = s;
    }
  } else {
    for (int i = threadIdx.x; i < NBINS; i += 256) gcur[i] = 0;
  }
}

// ======== fused: edge binning (blocks 0..NBLK-1) | MFMA GEMM (rest) ==========
// Independent work merged into one dispatch so they run concurrently.
// LDS: bin path needs 2*NBINS ints (3.1KB) which aliases the gemm path's
// 17.4KB epilogue repack buffer.
__global__ __launch_bounds__(256) void fused_bin_gemm(
    const int* __restrict__ src, const int* __restrict__ dst,
    int* __restrict__ gcur, uint* __restrict__ ebuf,
    const float* __restrict__ x, const ushort* __restrict__ W1T,
    ushort* __restrict__ y16, int M) {
  __shared__ ushort ly[4][16][136];            // 17408 B, shared by both paths

  if (blockIdx.x < NBLK) {
    // ---------------- bin_scatter path ----------------
    int* hist = (int*)&ly[0][0][0];
    int* base = hist + NBINS;
    for (int i = threadIdx.x; i < NBINS; i += 256) hist[i] = 0;
    __syncthreads();
    int e0 = blockIdx.x * EPB;
    int e1 = e0 + EPB; if (e1 > N_EDGES) e1 = N_EDGES;
    for (int e = e0 + threadIdx.x; e < e1; e += 256)
      atomicAdd(&hist[dst[e] >> 7], 1);
    __syncthreads();
    for (int i = threadIdx.x; i < NBINS; i += 256) {
      int c = hist[i];
      base[i] = (c > 0) ? atomicAdd(&gcur[i], c) : 0;
      hist[i] = 0;
    }
    __syncthreads();
    for (int e = e0 + threadIdx.x; e < e1; e += 256) {
      int d = dst[e];
      int b = d >> 7;
      int loc = atomicAdd(&hist[b], 1);
      ebuf[(size_t)b * BINCAP + base[b] + loc] = ((uint)d << 16) | (uint)src[e];
    }
    return;
  }

  // ---------------- gemm path ----------------
  const int bid = blockIdx.x - NBLK;
  const int tid = threadIdx.x;
  const int w = tid >> 6, l = tid & 63;
  const int row0 = bid * 64 + w * 16;
  const int mrow = l & 15, kg = l >> 4;
  const int row = row0 + mrow;

  f32x4 acc[8] = {};
  for (int kc = 0; kc < 4; ++kc) {
    const int cb = kc * 32 + kg * 8;
    f16x8 af = {};
    if (row < M) {
      float4 xlo = *(const float4*)(x + (size_t)row * 128 + cb);
      float4 xhi = *(const float4*)(x + (size_t)row * 128 + cb + 4);
      af[0] = (f16)xlo.x; af[1] = (f16)xlo.y; af[2] = (f16)xlo.z; af[3] = (f16)xlo.w;
      af[4] = (f16)xhi.x; af[5] = (f16)xhi.y; af[6] = (f16)xhi.z; af[7] = (f16)xhi.w;
    }
#pragma unroll
    for (int nt = 0; nt < 8; ++nt) {
      uint4 wb = *(const uint4*)(W1T + ((nt * 16 + mrow) << 7) + cb);
      f16x8 bf = *(const f16x8*)&wb;
      acc[nt] = __builtin_amdgcn_mfma_f32_16x16x32_f16(af, bf, acc[nt], 0, 0, 0);
    }
  }
  // D layout: col = lane&15 (mrow), row = (lane>>4)*4 + r (kg)
#pragma unroll
  for (int nt = 0; nt < 8; ++nt)
#pragma unroll
    for (int r = 0; r < 4; ++r)
      ly[w][kg * 4 + r][nt * 16 + mrow] = f2h(acc[nt][r]);
  __syncthreads();
  // coalesced store: 16 rows x 32 uint2 per wave, 8 per lane (uint2 = 4 ushort)
#pragma unroll
  for (int t = 0; t < 8; ++t) {
    int idx = t * 64 + l;
    int r2 = idx >> 5, c2 = idx & 31;
    int gr = row0 + r2;
    if (gr < M)
      ((uint2*)y16)[(size_t)gr * 32 + c2] = *(const uint2*)&ly[w][r2][c2 * 4];
  }
}

// ======== CSR build B: one block per bin -> col16 window + deg ===============
__global__ __launch_bounds__(256) void csr_from_bins(const uint* __restrict__ ebuf,
                                                     const int* __restrict__ gcur,
                                                     int* __restrict__ deg,
                                                     ushort* __restrict__ col16) {
  __shared__ int dl[128];
  const int bin = blockIdx.x;
  const int n0 = bin << 7;
  if (threadIdx.x < 128) dl[threadIdx.x] = 0;
  __syncthreads();
  int cnt_e = gcur[bin];
  int j0 = bin * BINCAP;
  for (int j = j0 + threadIdx.x; j < j0 + cnt_e; j += 256) {
    uint e = ebuf[j];
    int d = (int)(e >> 16);
    int slot = atomicAdd(&dl[d - n0], 1);
    col16[(size_t)d * STRIDE + slot] = (ushort)(e & 0xFFFFu);
  }
  __syncthreads();
  int cnt = N_NODES - n0; if (cnt > 128) cnt = 128;
  if (threadIdx.x < cnt) deg[n0 + threadIdx.x] = dl[threadIdx.x];
}

// ------- gather + relu + dot: q[n] = relu( sum_slots y16[col16[n][j]] ) . v --
// Predicated 8-slot preload: every row-load a lane will need (deg<=32) issues
// back-to-back before any accumulate -> up to 32 loads in flight per wave.
__global__ __launch_bounds__(256) void gather_qdot(const ushort* __restrict__ y16,
                                                   const int* __restrict__ deg,
                                                   const ushort* __restrict__ col16,
                                                   const float* __restrict__ vq,
                                                   float* __restrict__ q) {
  int n = (blockIdx.x * 256 + threadIdx.x) >> 6;
  if (n >= N_NODES) return;
  const int lane = threadIdx.x & 63;
  const int eg = lane >> 4;    // 0..3 edge group
  const int fl = lane & 15;    // feat lane: 8 fp16 = 16B

  int dg = deg[n];
  const ushort* cp = col16 + (size_t)n * STRIDE;
  h2 ah[4] = {};

  uint4 u[8];
#pragma unroll
  for (int k = 0; k < 8; ++k) {
    int j = eg + k * 4;
    if (j < dg) u[k] = ((const uint4*)y16)[(size_t)cp[j] * 16 + fl];
  }
#pragma unroll
  for (int k = 0; k < 8; ++k) {
    int j = eg + k * 4;
    if (j < dg) acc4h(ah, u[k]);
  }
  // tail for deg > 32 (P ~ 1e-4 per node)
  for (int j = eg + 32; j < dg; j += 4) {
    uint4 a = ((const uint4*)y16)[(size_t)cp[j] * 16 + fl];
    acc4h(ah, a);
  }

#pragma unroll
  for (int k = 0; k < 4; ++k) {
    UH2 c, t;
    c.h = ah[k];
    t.u = (uint)__shfl_xor((int)c.u, 16, 64); ah[k] += t.h;
    c.h = ah[k];
    t.u = (uint)__shfl_xor((int)c.u, 32, 64); ah[k] += t.h;
  }
  float4 v0 = ((const float4*)vq)[fl * 2];
  float4 v1 = ((const float4*)vq)[fl * 2 + 1];
  float p = fmaxf((float)ah[0].x, 0.f) * v0.x + fmaxf((float)ah[0].y, 0.f) * v0.y +
            fmaxf((float)ah[1].x, 0.f) * v0.z + fmaxf((float)ah[1].y, 0.f) * v0.w +
            fmaxf((float)ah[2].x, 0.f) * v1.x + fmaxf((float)ah[2].y, 0.f) * v1.y +
            fmaxf((float)ah[3].x, 0.f) * v1.z + fmaxf((float)ah[3].y, 0.f) * v1.w;
  p += __shfl_xor(p, 1, 64);
  p += __shfl_xor(p, 2, 64);
  p += __shfl_xor(p, 4, 64);
  p += __shfl_xor(p, 8, 64);
  if (lane == 0) q[n] = p;
}

// ------- pool: out[g] = sigmoid( (sum over graph-g edges of q[src]) / cnt ) --
__global__ __launch_bounds__(256) void pool_q(const float* __restrict__ q,
                                              const int* __restrict__ deg,
                                              const ushort* __restrict__ col16,
                                              const int* __restrict__ batch,
                                              float* __restrict__ out) {
  __shared__ float red[4];
  int g = blockIdx.x, tid = threadIdx.x;

  int lo = 0, hi = N_NODES;
  while (lo < hi) { int m = (lo + hi) >> 1; if (batch[m] < g) lo = m + 1; else hi = m; }
  int s0 = lo;
  lo = 0; hi = N_NODES;
  while (lo < hi) { int m = (lo + hi) >> 1; if (batch[m] <= g) lo = m + 1; else hi = m; }
  int s1 = lo;

  float sum = 0.f;
  for (int n = s0 + (tid >> 3); n < s1; n += 32) {
    int dg = deg[n];
    const ushort* cp = col16 + (size_t)n * STRIDE;
    for (int j = tid & 7; j < dg; j += 8) sum += q[cp[j]];
  }
#pragma unroll
  for (int off = 32; off > 0; off >>= 1) sum += __shfl_down(sum, off, 64);
  if ((tid & 63) == 0) red[tid >> 6] = sum;
  __syncthreads();
  if (tid == 0) {
    float z = red[0] + red[1] + red[2] + red[3];
    float cnt = fmaxf((float)(s1 - s0), 1.0f);
    z /= cnt;
    out[g] = 1.0f / (1.0f + expf(-z));
  }
}

extern "C" void kernel_launch(void* const* d_in, const int* in_sizes, int n_in,
                              void* d_out, int out_size, void* d_ws, size_t ws_size,
                              hipStream_t stream) {
  const float* x   = (const float*)d_in[0];
  const int*   ei  = (const int*)d_in[1];
  const int*   src = ei;               // edge_index[0]
  const int*   dst = ei + N_EDGES;     // edge_index[1]
  const int* batch = (const int*)d_in[2];
  const float* W1  = (const float*)d_in[3];
  const float* W2  = (const float*)d_in[4];
  const float* Wfc = (const float*)d_in[5];
  float* out = (float*)d_out;

  ushort* y16  = (ushort*)d_ws;                          // 6.4M fp16
  ushort* col16 = y16 + (size_t)N_NODES * NF;            // 50000*64 ushort
  int* deg     = (int*)(col16 + (size_t)N_NODES * STRIDE); // 50000
  float* q     = (float*)(deg + N_NODES);                // 50000
  float* v     = q + N_NODES;                            // 128
  ushort* W1T  = (ushort*)(v + NF + 32);                 // 16384 fp16
  int* gcur    = (int*)(W1T + 16384 + 64);               // NBINS
  uint* ebuf   = (uint*)(gcur + NBINS + 32);             // NBINS*BINCAP u32

  const int gemm_grid = (N_NODES + 63) / 64;            // 782
  const int gath_grid = (N_NODES * 64 + 255) / 256;     // 12500

  // --- prep: W1T, v, gcur=0 in one kernel ---
  prep<<<66, 256, 0, stream>>>(W1, W2, Wfc, W1T, v, gcur);

  // --- fused: edge binning || dense MFMA GEMM (independent, one dispatch) ---
  fused_bin_gemm<<<NBLK + gemm_grid, 256, 0, stream>>>(src, dst, gcur, ebuf,
                                                       x, W1T, y16, N_NODES);

  // --- CSR finalize: per-bin single-block fill ---
  csr_from_bins<<<NBINS, 256, 0, stream>>>(ebuf, gcur, deg, col16);

  // --- conv1 aggregate + relu + (W2@Wfc) dot, fused per node ---
  gather_qdot<<<gath_grid, 256, 0, stream>>>(y16, deg, col16, v, q);

  // --- conv2 + pool + fc + sigmoid: scalar gather over L2-resident q ---
  pool_q<<<N_GRAPHS, 256, 0, stream>>>(q, deg, col16, batch, out);
}